// Round 4
// baseline (1101.078 us; speedup 1.0000x reference)
//
#include <hip/hip_runtime.h>
#include <float.h>
#include <math.h>

#define C     1024
#define NQ    10
#define G4    512              // fused-kernel blocks (2/CU); 1024 wave-pairs
#define NPAIR (G4 * 2)

// ---- wave64 sum via DPP (pure VALU; result broadcast via readlane) --------
template <int CTRL, int ROWM>
__device__ __forceinline__ float dpp_add(float x) {
  int mv = __builtin_amdgcn_update_dpp(0, __float_as_int(x), CTRL, ROWM, 0xf, true);
  return x + __int_as_float(mv);
}
__device__ __forceinline__ float wave_sum64(float x) {
  x = dpp_add<0xB1,  0xf>(x);  // quad_perm [1,0,3,2]  (xor 1)
  x = dpp_add<0x4E,  0xf>(x);  // quad_perm [2,3,0,1]  (xor 2)
  x = dpp_add<0x141, 0xf>(x);  // row_half_mirror      (xor-pair 4)
  x = dpp_add<0x140, 0xf>(x);  // row_mirror           (xor-pair 8)
  x = dpp_add<0x142, 0xa>(x);  // row_bcast15 -> rows 1,3
  x = dpp_add<0x143, 0xc>(x);  // row_bcast31 -> rows 2,3
  return __int_as_float(__builtin_amdgcn_readlane(__float_as_int(x), 63));
}

__device__ __forceinline__ void scale4(float4& v, float s) {
  v.x *= s; v.y *= s; v.z *= s; v.w *= s;
}
__device__ __forceinline__ void fma4(float4& acc, float w, const float4& x) {
  acc.x = fmaf(w, x.x, acc.x); acc.y = fmaf(w, x.y, acc.y);
  acc.z = fmaf(w, x.z, acc.z); acc.w = fmaf(w, x.w, acc.w);
}

// ---------------- K0: qd[k] = Qn[k] - Qn[NQ] -------------------------------
__global__ __launch_bounds__(256) void k0_qdiff(const float* __restrict__ Q,
                                                float* __restrict__ qd) {
  __shared__ float red[256];
  __shared__ float inorm[NQ + 1];
  int t = threadIdx.x;
  for (int k = 0; k <= NQ; ++k) {
    float s = 0.f;
    for (int c = t; c < C; c += 256) { float v = Q[k * C + c]; s = fmaf(v, v, s); }
    red[t] = s; __syncthreads();
    for (int st = 128; st > 0; st >>= 1) {
      if (t < st) red[t] += red[t + st];
      __syncthreads();
    }
    if (t == 0) inorm[k] = 1.0f / fmaxf(sqrtf(red[0]), 1e-12f);
    __syncthreads();
  }
  for (int k = 0; k < NQ; ++k)
    for (int c = t; c < C; c += 256)
      qd[k * C + c] = Q[k * C + c] * inorm[k] - Q[NQ * C + c] * inorm[NQ];
}

// ---------------- KF2: single-pass online-softmax, zero main-loop barriers -
// Wave-PAIR per row: both waves of pair (wv&1 selects 5-query group) load the
// same row (second hits L1/L2); each lane owns 16 columns. After the DPP
// logit reduction, lg is wave-uniform, so each wave maintains its OWN running
// max mo[k] / denom ds[k] / accumulators a[k][4] and folds w*x straight from
// the dot-product registers: X streams from HBM exactly once, no phase B.
// Rescale (exp(mo-mn) over 80 regs) only on max growth: ~5 events/query/wave.
// Cross-wave + cross-block max skew fixed exactly in combine via exp(m-M).
__global__ __launch_bounds__(256, 2) void kf_fused(const float* __restrict__ X,
                                                   const float* __restrict__ qd,
                                                   float* __restrict__ partial,
                                                   float* __restrict__ dsum,
                                                   float* __restrict__ mblk,
                                                   int N) {
  const int t = threadIdx.x;
  const int l = t & 63, wv = t >> 6;
  const int pr = wv >> 1;                 // pair id within block
  const int qbase = (wv & 1) * 5;         // query group: 0..4 or 5..9
  const int co = l << 2;
  const int pid = blockIdx.x * 2 + pr;    // global pair id in [0, NPAIR)

  float4 q4[5][4];                        // 80 VGPRs of query fragments
#pragma unroll
  for (int k = 0; k < 5; ++k)
#pragma unroll
    for (int j = 0; j < 4; ++j)
      q4[k][j] = *(const float4*)(qd + (qbase + k) * C + j * 256 + co);

  float4 a[5][4];                         // 80 VGPRs: 5 queries x 16 cols/lane
  float ds[5], mo[5];
#pragma unroll
  for (int k = 0; k < 5; ++k) {
    a[k][0] = a[k][1] = a[k][2] = a[k][3] = make_float4(0.f, 0.f, 0.f, 0.f);
    ds[k] = 0.f; mo[k] = -FLT_MAX;
  }

  // row load: 4x dwordx4, lane l spans the full 4KB row
  auto loadrow = [&](float4* dst, int rr) {
    const float* xp = X + (size_t)rr * C + co;
    dst[0] = *(const float4*)(xp);
    dst[1] = *(const float4*)(xp + 256);
    dst[2] = *(const float4*)(xp + 512);
    dst[3] = *(const float4*)(xp + 768);
  };

  // process one row already in registers
  auto proc = [&](const float4* xv) {
    float ss = 0.f;
    float dt[5];
#pragma unroll
    for (int k = 0; k < 5; ++k) dt[k] = 0.f;
#pragma unroll
    for (int j = 0; j < 4; ++j) {
      float4 v = xv[j];
      ss = fmaf(v.x, v.x, fmaf(v.y, v.y, fmaf(v.z, v.z, fmaf(v.w, v.w, ss))));
#pragma unroll
      for (int k = 0; k < 5; ++k) {
        float4 q = q4[k][j];
        dt[k] = fmaf(v.x, q.x, fmaf(v.y, q.y, fmaf(v.z, q.z, fmaf(v.w, q.w, dt[k]))));
      }
    }
    float rn = 100.0f / fmaxf(sqrtf(wave_sum64(ss)), 1e-12f);
#pragma unroll
    for (int k = 0; k < 5; ++k) {
      float lg = wave_sum64(dt[k]) * rn;  // wave-uniform (readlane broadcast)
      float mn = fmaxf(mo[k], lg);
      if (mn > mo[k]) {                   // wave-uniform branch
        float sc = __expf(mo[k] - mn);    // first row: exp(-inf) = 0
        ds[k] *= sc;
        scale4(a[k][0], sc); scale4(a[k][1], sc);
        scale4(a[k][2], sc); scale4(a[k][3], sc);
        mo[k] = mn;
      }
      float w = __expf(lg - mo[k]);
      ds[k] += w;
      fma4(a[k][0], w, xv[0]); fma4(a[k][1], w, xv[1]);
      fma4(a[k][2], w, xv[2]); fma4(a[k][3], w, xv[3]);
    }
  };

  // ---- main loop: ping-pong prefetch, no barriers, no LDS ----
  {
    float4 xa[4], xb[4];
    int r = pid;                          // pid < NPAIR <= N always
    loadrow(xa, r);
    int rn = r + NPAIR;
    for (;;) {
      if (rn < N) loadrow(xb, rn);
      proc(xa);                           // row r
      if (rn >= N) break;
      r = rn; rn = r + NPAIR;
      if (rn < N) loadrow(xa, rn);
      proc(xb);                           // row r
      if (rn >= N) break;
      r = rn; rn = r + NPAIR;
    }
  }

  // ---- block combine: waves {0,2} own q0-4, {1,3} own q5-9 ----
  __shared__ float wm[4][8];
  __shared__ float wd[4][8];
  __shared__ float part[NQ][C];           // 40 KB
  if (l == 0) {
#pragma unroll
    for (int k = 0; k < 5; ++k) { wm[wv][k] = mo[k]; wd[wv][k] = ds[k]; }
  }
  __syncthreads();
  float sc[5];
#pragma unroll
  for (int k = 0; k < 5; ++k) {
    float M = fmaxf(wm[wv][k], wm[wv ^ 2][k]);
    sc[k] = __expf(mo[k] - M);
  }
  if (wv < 2) {
#pragma unroll
    for (int k = 0; k < 5; ++k)
#pragma unroll
      for (int j = 0; j < 4; ++j) {
        float4 o = a[k][j]; scale4(o, sc[k]);
        *(float4*)&part[qbase + k][j * 256 + co] = o;
      }
  }
  __syncthreads();
  if (wv >= 2) {
#pragma unroll
    for (int k = 0; k < 5; ++k)
#pragma unroll
      for (int j = 0; j < 4; ++j) {
        float4 p = *(const float4*)&part[qbase + k][j * 256 + co];
        float4 o = a[k][j];
        p.x = fmaf(o.x, sc[k], p.x); p.y = fmaf(o.y, sc[k], p.y);
        p.z = fmaf(o.z, sc[k], p.z); p.w = fmaf(o.w, sc[k], p.w);
        *(float4*)&part[qbase + k][j * 256 + co] = p;
      }
  }
  __syncthreads();

  // coalesced write-out of block partial [NQ][C]
  {
    const float4* src = (const float4*)&part[0][0];
    float4* dst = (float4*)&partial[(size_t)blockIdx.x * NQ * C];
    for (int idx = t; idx < NQ * (C / 4); idx += 256) dst[idx] = src[idx];
  }
  if (t < NQ) {
    int w0 = (t < 5) ? 0 : 1, k5 = (t < 5) ? t : t - 5;
    float m0 = wm[w0][k5], m1 = wm[w0 + 2][k5];
    float M = fmaxf(m0, m1);
    dsum[blockIdx.x * NQ + t] =
        wd[w0][k5] * __expf(m0 - M) + wd[w0 + 2][k5] * __expf(m1 - M);
    mblk[blockIdx.x * 16 + t] = M;
  }
}

// ---------------- K5a: combine partials with per-block max correction ------
// pooled[c] = sum_k [ sum_g exp(m_g-M_k) a_g[k][c] ] / (NQ * D_k),
//   D_k = sum_g exp(m_g-M_k) ds_g[k],  M_k = max_g m_g[k]
__global__ __launch_bounds__(256) void k5a_pooled(const float* __restrict__ partial,
                                                  const float* __restrict__ dsum,
                                                  const float* __restrict__ mblk,
                                                  float* __restrict__ pooled) {
  __shared__ float sM[16], sF[16];
  __shared__ float red[256];
  __shared__ float r4[256][4];
  int t = threadIdx.x;
  int k = t & 15, grp = t >> 4;

  float mm = -FLT_MAX;
  if (k < NQ)
    for (int g = grp; g < G4; g += 16) mm = fmaxf(mm, mblk[g * 16 + k]);
  red[t] = mm; __syncthreads();
  if (t < 16) {
    float m2 = red[t];
    for (int j = 1; j < 16; ++j) m2 = fmaxf(m2, red[t + 16 * j]);
    sM[t] = m2;
  }
  __syncthreads();

  float dd = 0.f;
  if (k < NQ) {
    float Mk = sM[k];
    for (int g = grp; g < G4; g += 16)
      dd += dsum[g * NQ + k] * __expf(mblk[g * 16 + k] - Mk);
  }
  red[t] = dd; __syncthreads();
  if (t < 16) {
    float d2 = 0.f;
    for (int j = 0; j < 16; ++j) d2 += red[t + 16 * j];
    sF[t] = 1.0f / ((float)NQ * d2);      // only t<NQ entries are consumed
  }
  __syncthreads();

  int c0 = blockIdx.x * 4;
  float a0 = 0.f, a1 = 0.f, a2 = 0.f, a3 = 0.f;
  for (int idx = t; idx < G4 * NQ; idx += 256) {
    int g = idx / NQ, kq = idx - g * NQ;
    float f = __expf(mblk[g * 16 + kq] - sM[kq]) * sF[kq];
    const float4 p = *(const float4*)&partial[(((size_t)idx) << 10) + c0];
    a0 = fmaf(p.x, f, a0); a1 = fmaf(p.y, f, a1);
    a2 = fmaf(p.z, f, a2); a3 = fmaf(p.w, f, a3);
  }
  r4[t][0] = a0; r4[t][1] = a1; r4[t][2] = a2; r4[t][3] = a3;
  __syncthreads();
  for (int st = 128; st > 0; st >>= 1) {
    if (t < st) {
      r4[t][0] += r4[t + st][0]; r4[t][1] += r4[t + st][1];
      r4[t][2] += r4[t + st][2]; r4[t][3] += r4[t + st][3];
    }
    __syncthreads();
  }
  if (t < 4) pooled[c0 + t] = r4[0][t];
}

// ---------------- K5b: out[j] = b[j] + sum_c pooled[c] * W[j][c] -----------
__global__ __launch_bounds__(256) void k5b_out(const float* __restrict__ W,
                                               const float* __restrict__ bias,
                                               const float* __restrict__ pooled,
                                               float* __restrict__ out) {
  __shared__ float sp[C];
  int t = threadIdx.x;
  for (int i = t; i < C; i += 256) sp[i] = pooled[i];
  __syncthreads();
  int wv = t >> 6, lane = t & 63;
#pragma unroll
  for (int jj = 0; jj < 8; ++jj) {
    int j = blockIdx.x * 32 + wv * 8 + jj;
    float s = 0.f;
#pragma unroll
    for (int seg = 0; seg < 4; ++seg) {
      int cbase = seg * 256 + lane * 4;
      float4 w4 = *(const float4*)&W[(size_t)j * C + cbase];
      float4 p4 = *(const float4*)&sp[cbase];
      s += w4.x * p4.x + w4.y * p4.y + w4.z * p4.z + w4.w * p4.w;
    }
#pragma unroll
    for (int off = 32; off > 0; off >>= 1) s += __shfl_down(s, off);
    if (lane == 0) out[j] = s + bias[j];
  }
}

// ---------------------------------------------------------------------------
extern "C" void kernel_launch(void* const* d_in, const int* in_sizes, int n_in,
                              void* d_out, int out_size, void* d_ws, size_t ws_size,
                              hipStream_t stream) {
  const float* X = (const float*)d_in[0];
  const float* Q = (const float*)d_in[1];
  const float* W = (const float*)d_in[2];
  const float* b = (const float*)d_in[3];
  float* out = (float*)d_out;

  int N = in_sizes[0] / C;                 // 100000

  float* ws      = (float*)d_ws;
  float* qd      = ws;                               // NQ*C
  float* mblk    = qd + NQ * C;                      // G4*16
  float* dsum    = mblk + G4 * 16;                   // G4*NQ
  float* pooled  = dsum + G4 * NQ;                   // C
  float* partial = pooled + C;                       // G4*NQ*C (~21 MB)

  hipLaunchKernelGGL(k0_qdiff,  dim3(1),      dim3(256), 0, stream, Q, qd);
  hipLaunchKernelGGL(kf_fused,  dim3(G4),     dim3(256), 0, stream,
                     X, qd, partial, dsum, mblk, N);
  hipLaunchKernelGGL(k5a_pooled,dim3(C / 4),  dim3(256), 0, stream,
                     partial, dsum, mblk, pooled);
  hipLaunchKernelGGL(k5b_out,   dim3(C / 32), dim3(256), 0, stream, W, b, pooled, out);
}

// Round 5
// 650.869 us; speedup vs baseline: 1.6917x; 1.6917x over previous
//
#include <hip/hip_runtime.h>
#include <float.h>
#include <math.h>

#define C     1024
#define NQ    10
#define G4    512              // fused-kernel blocks (2/CU); 1024 wave-pairs
#define NPAIR (G4 * 2)

// ---- wave64 sum via DPP (pure VALU; result broadcast via readlane) --------
template <int CTRL, int ROWM>
__device__ __forceinline__ float dpp_add(float x) {
  int mv = __builtin_amdgcn_update_dpp(0, __float_as_int(x), CTRL, ROWM, 0xf, true);
  return x + __int_as_float(mv);
}
__device__ __forceinline__ float wave_sum64(float x) {
  x = dpp_add<0xB1,  0xf>(x);  // quad_perm [1,0,3,2]  (xor 1)
  x = dpp_add<0x4E,  0xf>(x);  // quad_perm [2,3,0,1]  (xor 2)
  x = dpp_add<0x141, 0xf>(x);  // row_half_mirror      (xor-pair 4)
  x = dpp_add<0x140, 0xf>(x);  // row_mirror           (xor-pair 8)
  x = dpp_add<0x142, 0xa>(x);  // row_bcast15 -> rows 1,3
  x = dpp_add<0x143, 0xc>(x);  // row_bcast31 -> rows 2,3
  return __int_as_float(__builtin_amdgcn_readlane(__float_as_int(x), 63));
}

__device__ __forceinline__ void scale4(float4& v, float s) {
  v.x *= s; v.y *= s; v.z *= s; v.w *= s;
}
__device__ __forceinline__ void fma4(float4& acc, float w, const float4& x) {
  acc.x = fmaf(w, x.x, acc.x); acc.y = fmaf(w, x.y, acc.y);
  acc.z = fmaf(w, x.z, acc.z); acc.w = fmaf(w, x.w, acc.w);
}

// ---------------- K0: qd[k] = Qn[k] - Qn[NQ] -------------------------------
__global__ __launch_bounds__(256) void k0_qdiff(const float* __restrict__ Q,
                                                float* __restrict__ qd) {
  __shared__ float red[256];
  __shared__ float inorm[NQ + 1];
  int t = threadIdx.x;
  for (int k = 0; k <= NQ; ++k) {
    float s = 0.f;
    for (int c = t; c < C; c += 256) { float v = Q[k * C + c]; s = fmaf(v, v, s); }
    red[t] = s; __syncthreads();
    for (int st = 128; st > 0; st >>= 1) {
      if (t < st) red[t] += red[t + st];
      __syncthreads();
    }
    if (t == 0) inorm[k] = 1.0f / fmaxf(sqrtf(red[0]), 1e-12f);
    __syncthreads();
  }
  for (int k = 0; k < NQ; ++k)
    for (int c = t; c < C; c += 256)
      qd[k * C + c] = Q[k * C + c] * inorm[k] - Q[NQ * C + c] * inorm[NQ];
}

// ---------------- KF3: single-pass online-softmax, no prefetch buffers -----
// Wave-PAIR per row: both waves of a pair load the same row (HBM sees one
// fetch; pair is on the same CU). Each wave owns 5 queries (q frags 80 VGPR)
// and 16 row-columns/lane. After the DPP logit reduction lg is wave-uniform,
// so each wave keeps its OWN running max mo[k]/denom ds[k]/acc a[k][4] and
// folds w*x straight from the dot registers: X streams from HBM exactly once,
// zero barriers and zero LDS in the main loop. NO software ping-pong: R4
// showed it spilled (VGPR 128 + 1.4 GB scratch writes). TLP (2 waves/SIMD,
// 4 dwordx4 in flight per wave) provides the MLP instead. #pragma unroll 1
// keeps the unroller from re-creating the pressure.
// Cross-wave + cross-block max skew fixed exactly in combine via exp(m-M).
__global__ __launch_bounds__(256, 2) void kf_fused(const float* __restrict__ X,
                                                   const float* __restrict__ qd,
                                                   float* __restrict__ partial,
                                                   float* __restrict__ dsum,
                                                   float* __restrict__ mblk,
                                                   int N) {
  const int t = threadIdx.x;
  const int l = t & 63, wv = t >> 6;
  const int pr = wv >> 1;                 // pair id within block
  const int qbase = (wv & 1) * 5;         // query group: 0..4 or 5..9
  const int co = l << 2;
  const int pid = blockIdx.x * 2 + pr;    // global pair id in [0, NPAIR)

  float4 q4[5][4];                        // 80 VGPRs of query fragments
#pragma unroll
  for (int k = 0; k < 5; ++k)
#pragma unroll
    for (int j = 0; j < 4; ++j)
      q4[k][j] = *(const float4*)(qd + (qbase + k) * C + j * 256 + co);

  float4 a[5][4];                         // 80 VGPRs: 5 queries x 16 cols/lane
  float ds[5], mo[5];
#pragma unroll
  for (int k = 0; k < 5; ++k) {
    a[k][0] = a[k][1] = a[k][2] = a[k][3] = make_float4(0.f, 0.f, 0.f, 0.f);
    ds[k] = 0.f; mo[k] = -FLT_MAX;
  }

#pragma unroll 1
  for (int r = pid; r < N; r += NPAIR) {
    const float* xp = X + (size_t)r * C + co;
    float4 xv[4];
#pragma unroll
    for (int j = 0; j < 4; ++j) xv[j] = *(const float4*)(xp + j * 256);

    float ss = 0.f;
    float dt[5];
#pragma unroll
    for (int k = 0; k < 5; ++k) dt[k] = 0.f;
#pragma unroll
    for (int j = 0; j < 4; ++j) {
      float4 v = xv[j];
      ss = fmaf(v.x, v.x, fmaf(v.y, v.y, fmaf(v.z, v.z, fmaf(v.w, v.w, ss))));
#pragma unroll
      for (int k = 0; k < 5; ++k) {
        float4 q = q4[k][j];
        dt[k] = fmaf(v.x, q.x, fmaf(v.y, q.y, fmaf(v.z, q.z, fmaf(v.w, q.w, dt[k]))));
      }
    }
    float rn = 100.0f / fmaxf(sqrtf(wave_sum64(ss)), 1e-12f);
#pragma unroll
    for (int k = 0; k < 5; ++k) {
      float lg = wave_sum64(dt[k]) * rn;  // wave-uniform (readlane broadcast)
      float mn = fmaxf(mo[k], lg);
      if (mn > mo[k]) {                   // wave-uniform branch, rare
        float sc = __expf(mo[k] - mn);    // first row: exp(-inf) = 0
        ds[k] *= sc;
        scale4(a[k][0], sc); scale4(a[k][1], sc);
        scale4(a[k][2], sc); scale4(a[k][3], sc);
        mo[k] = mn;
      }
      float w = __expf(lg - mo[k]);
      ds[k] += w;
      fma4(a[k][0], w, xv[0]); fma4(a[k][1], w, xv[1]);
      fma4(a[k][2], w, xv[2]); fma4(a[k][3], w, xv[3]);
    }
  }

  // ---- block combine: waves {0,2} own q0-4, {1,3} own q5-9 ----
  __shared__ float wm[4][8];
  __shared__ float wd[4][8];
  __shared__ float part[NQ][C];           // 40 KB
  if (l == 0) {
#pragma unroll
    for (int k = 0; k < 5; ++k) { wm[wv][k] = mo[k]; wd[wv][k] = ds[k]; }
  }
  __syncthreads();
  float sc[5];
#pragma unroll
  for (int k = 0; k < 5; ++k) {
    float M = fmaxf(wm[wv][k], wm[wv ^ 2][k]);
    sc[k] = __expf(mo[k] - M);
  }
  if (wv < 2) {
#pragma unroll
    for (int k = 0; k < 5; ++k)
#pragma unroll
      for (int j = 0; j < 4; ++j) {
        float4 o = a[k][j]; scale4(o, sc[k]);
        *(float4*)&part[qbase + k][j * 256 + co] = o;
      }
  }
  __syncthreads();
  if (wv >= 2) {
#pragma unroll
    for (int k = 0; k < 5; ++k)
#pragma unroll
      for (int j = 0; j < 4; ++j) {
        float4 p = *(const float4*)&part[qbase + k][j * 256 + co];
        float4 o = a[k][j];
        p.x = fmaf(o.x, sc[k], p.x); p.y = fmaf(o.y, sc[k], p.y);
        p.z = fmaf(o.z, sc[k], p.z); p.w = fmaf(o.w, sc[k], p.w);
        *(float4*)&part[qbase + k][j * 256 + co] = p;
      }
  }
  __syncthreads();

  // coalesced write-out of block partial [NQ][C]
  {
    const float4* src = (const float4*)&part[0][0];
    float4* dst = (float4*)&partial[(size_t)blockIdx.x * NQ * C];
    for (int idx = t; idx < NQ * (C / 4); idx += 256) dst[idx] = src[idx];
  }
  if (t < NQ) {
    int w0 = (t < 5) ? 0 : 1, k5 = (t < 5) ? t : t - 5;
    float m0 = wm[w0][k5], m1 = wm[w0 + 2][k5];
    float M = fmaxf(m0, m1);
    dsum[blockIdx.x * NQ + t] =
        wd[w0][k5] * __expf(m0 - M) + wd[w0 + 2][k5] * __expf(m1 - M);
    mblk[blockIdx.x * 16 + t] = M;
  }
}

// ---------------- K5a: combine partials with per-block max correction ------
// pooled[c] = sum_k [ sum_g exp(m_g-M_k) a_g[k][c] ] / (NQ * D_k),
//   D_k = sum_g exp(m_g-M_k) ds_g[k],  M_k = max_g m_g[k]
__global__ __launch_bounds__(256) void k5a_pooled(const float* __restrict__ partial,
                                                  const float* __restrict__ dsum,
                                                  const float* __restrict__ mblk,
                                                  float* __restrict__ pooled) {
  __shared__ float sM[16], sF[16];
  __shared__ float red[256];
  __shared__ float r4[256][4];
  int t = threadIdx.x;
  int k = t & 15, grp = t >> 4;

  float mm = -FLT_MAX;
  if (k < NQ)
    for (int g = grp; g < G4; g += 16) mm = fmaxf(mm, mblk[g * 16 + k]);
  red[t] = mm; __syncthreads();
  if (t < 16) {
    float m2 = red[t];
    for (int j = 1; j < 16; ++j) m2 = fmaxf(m2, red[t + 16 * j]);
    sM[t] = m2;
  }
  __syncthreads();

  float dd = 0.f;
  if (k < NQ) {
    float Mk = sM[k];
    for (int g = grp; g < G4; g += 16)
      dd += dsum[g * NQ + k] * __expf(mblk[g * 16 + k] - Mk);
  }
  red[t] = dd; __syncthreads();
  if (t < 16) {
    float d2 = 0.f;
    for (int j = 0; j < 16; ++j) d2 += red[t + 16 * j];
    sF[t] = 1.0f / ((float)NQ * d2);      // only t<NQ entries are consumed
  }
  __syncthreads();

  int c0 = blockIdx.x * 4;
  float a0 = 0.f, a1 = 0.f, a2 = 0.f, a3 = 0.f;
  for (int idx = t; idx < G4 * NQ; idx += 256) {
    int g = idx / NQ, kq = idx - g * NQ;
    float f = __expf(mblk[g * 16 + kq] - sM[kq]) * sF[kq];
    const float4 p = *(const float4*)&partial[(((size_t)idx) << 10) + c0];
    a0 = fmaf(p.x, f, a0); a1 = fmaf(p.y, f, a1);
    a2 = fmaf(p.z, f, a2); a3 = fmaf(p.w, f, a3);
  }
  r4[t][0] = a0; r4[t][1] = a1; r4[t][2] = a2; r4[t][3] = a3;
  __syncthreads();
  for (int st = 128; st > 0; st >>= 1) {
    if (t < st) {
      r4[t][0] += r4[t + st][0]; r4[t][1] += r4[t + st][1];
      r4[t][2] += r4[t + st][2]; r4[t][3] += r4[t + st][3];
    }
    __syncthreads();
  }
  if (t < 4) pooled[c0 + t] = r4[0][t];
}

// ---------------- K5b: out[j] = b[j] + sum_c pooled[c] * W[j][c] -----------
__global__ __launch_bounds__(256) void k5b_out(const float* __restrict__ W,
                                               const float* __restrict__ bias,
                                               const float* __restrict__ pooled,
                                               float* __restrict__ out) {
  __shared__ float sp[C];
  int t = threadIdx.x;
  for (int i = t; i < C; i += 256) sp[i] = pooled[i];
  __syncthreads();
  int wv = t >> 6, lane = t & 63;
#pragma unroll
  for (int jj = 0; jj < 8; ++jj) {
    int j = blockIdx.x * 32 + wv * 8 + jj;
    float s = 0.f;
#pragma unroll
    for (int seg = 0; seg < 4; ++seg) {
      int cbase = seg * 256 + lane * 4;
      float4 w4 = *(const float4*)&W[(size_t)j * C + cbase];
      float4 p4 = *(const float4*)&sp[cbase];
      s += w4.x * p4.x + w4.y * p4.y + w4.z * p4.z + w4.w * p4.w;
    }
#pragma unroll
    for (int off = 32; off > 0; off >>= 1) s += __shfl_down(s, off);
    if (lane == 0) out[j] = s + bias[j];
  }
}

// ---------------------------------------------------------------------------
extern "C" void kernel_launch(void* const* d_in, const int* in_sizes, int n_in,
                              void* d_out, int out_size, void* d_ws, size_t ws_size,
                              hipStream_t stream) {
  const float* X = (const float*)d_in[0];
  const float* Q = (const float*)d_in[1];
  const float* W = (const float*)d_in[2];
  const float* b = (const float*)d_in[3];
  float* out = (float*)d_out;

  int N = in_sizes[0] / C;                 // 100000

  float* ws      = (float*)d_ws;
  float* qd      = ws;                               // NQ*C
  float* mblk    = qd + NQ * C;                      // G4*16
  float* dsum    = mblk + G4 * 16;                   // G4*NQ
  float* pooled  = dsum + G4 * NQ;                   // C
  float* partial = pooled + C;                       // G4*NQ*C (~21 MB)

  hipLaunchKernelGGL(k0_qdiff,  dim3(1),      dim3(256), 0, stream, Q, qd);
  hipLaunchKernelGGL(kf_fused,  dim3(G4),     dim3(256), 0, stream,
                     X, qd, partial, dsum, mblk, N);
  hipLaunchKernelGGL(k5a_pooled,dim3(C / 4),  dim3(256), 0, stream,
                     partial, dsum, mblk, pooled);
  hipLaunchKernelGGL(k5b_out,   dim3(C / 32), dim3(256), 0, stream, W, b, pooled, out);
}

// Round 6
// 603.449 us; speedup vs baseline: 1.8246x; 1.0786x over previous
//
#include <hip/hip_runtime.h>
#include <float.h>
#include <math.h>

#define C     1024
#define NQ    10
#define G4    512              // fused-kernel blocks (2/CU); 1024 wave-pairs
#define NPAIR (G4 * 2)

// ---- wave64 sum via DPP (pure VALU; result broadcast via readlane) --------
template <int CTRL, int ROWM>
__device__ __forceinline__ float dpp_add(float x) {
  int mv = __builtin_amdgcn_update_dpp(0, __float_as_int(x), CTRL, ROWM, 0xf, true);
  return x + __int_as_float(mv);
}
__device__ __forceinline__ float wave_sum64(float x) {
  x = dpp_add<0xB1,  0xf>(x);  // quad_perm [1,0,3,2]  (xor 1)
  x = dpp_add<0x4E,  0xf>(x);  // quad_perm [2,3,0,1]  (xor 2)
  x = dpp_add<0x141, 0xf>(x);  // row_half_mirror      (xor-pair 4)
  x = dpp_add<0x140, 0xf>(x);  // row_mirror           (xor-pair 8)
  x = dpp_add<0x142, 0xa>(x);  // row_bcast15 -> rows 1,3
  x = dpp_add<0x143, 0xc>(x);  // row_bcast31 -> rows 2,3
  return __int_as_float(__builtin_amdgcn_readlane(__float_as_int(x), 63));
}

__device__ __forceinline__ void scale4(float4& v, float s) {
  v.x *= s; v.y *= s; v.z *= s; v.w *= s;
}
__device__ __forceinline__ void fma4(float4& acc, float w, const float4& x) {
  acc.x = fmaf(w, x.x, acc.x); acc.y = fmaf(w, x.y, acc.y);
  acc.z = fmaf(w, x.z, acc.z); acc.w = fmaf(w, x.w, acc.w);
}

// ---------------- KF4: single-pass online-softmax, 2-row MLP unroll --------
// Wave-PAIR per row: both waves of a pair load the same rows (one HBM fetch;
// pair is co-resident on the CU so the second hits L1/L2). Each wave owns 5
// queries and 16 row-columns/lane. Logits are wave-uniform after the DPP
// reduction, so each wave keeps its OWN running max mo[k]/denom ds[k]/acc
// a[k][4] -- X streams from HBM exactly once; zero barriers/LDS in the loop.
// R5 post-mortem: kernel was latency-bound (4KB in flight per wave, ~300cy
// dependent compute). Fix: manual 2-row unroll with NAMED x0/x1 arrays
// (straight-line, constant-indexed -- avoids R4's pointer-passed ping-pong
// spill) => 8KB in flight/wave; compiler emits vmcnt(4) before proc(x0) so
// x1's loads ride under x0's compute. Query prep (old k0) is folded into the
// prologue: each wave computes its own q4 fragments via DPP norms, no LDS.
__global__ __launch_bounds__(256, 2) void kf_fused(const float* __restrict__ X,
                                                   const float* __restrict__ Q,
                                                   float* __restrict__ partial,
                                                   float* __restrict__ dsum,
                                                   float* __restrict__ mblk,
                                                   int N) {
  const int t = threadIdx.x;
  const int l = t & 63, wv = t >> 6;
  const int pr = wv >> 1;                 // pair id within block
  const int qbase = (wv & 1) * 5;         // query group: 0..4 or 5..9
  const int co = l << 2;
  const int pid = blockIdx.x * 2 + pr;    // global pair id in [0, NPAIR)

  // ---- per-wave query prep (replaces k0): q4[k] = Qn[qbase+k] - Qn[NQ] ----
  float4 q4[5][4];                        // 80 VGPRs of query-diff fragments
  {
    float4 qn[4];
    float ssn = 0.f;
#pragma unroll
    for (int j = 0; j < 4; ++j) {
      qn[j] = *(const float4*)(Q + NQ * C + j * 256 + co);
      ssn = fmaf(qn[j].x, qn[j].x, fmaf(qn[j].y, qn[j].y,
            fmaf(qn[j].z, qn[j].z, fmaf(qn[j].w, qn[j].w, ssn))));
    }
    const float inN = 1.0f / fmaxf(sqrtf(wave_sum64(ssn)), 1e-12f);
#pragma unroll
    for (int k = 0; k < 5; ++k) {
      float4 qf[4];
      float ssq = 0.f;
#pragma unroll
      for (int j = 0; j < 4; ++j) {
        qf[j] = *(const float4*)(Q + (qbase + k) * C + j * 256 + co);
        ssq = fmaf(qf[j].x, qf[j].x, fmaf(qf[j].y, qf[j].y,
              fmaf(qf[j].z, qf[j].z, fmaf(qf[j].w, qf[j].w, ssq))));
      }
      const float ink = 1.0f / fmaxf(sqrtf(wave_sum64(ssq)), 1e-12f);
#pragma unroll
      for (int j = 0; j < 4; ++j) {
        q4[k][j].x = qf[j].x * ink - qn[j].x * inN;
        q4[k][j].y = qf[j].y * ink - qn[j].y * inN;
        q4[k][j].z = qf[j].z * ink - qn[j].z * inN;
        q4[k][j].w = qf[j].w * ink - qn[j].w * inN;
      }
    }
  }

  float4 a[5][4];                         // 80 VGPRs: 5 queries x 16 cols/lane
  float ds[5], mo[5];
#pragma unroll
  for (int k = 0; k < 5; ++k) {
    a[k][0] = a[k][1] = a[k][2] = a[k][3] = make_float4(0.f, 0.f, 0.f, 0.f);
    ds[k] = 0.f; mo[k] = -FLT_MAX;
  }

  // process one row held in registers (forceinline; all indices constant)
  auto proc = [&](const float4 (&xv)[4]) {
    float ss = 0.f;
    float dt[5];
#pragma unroll
    for (int k = 0; k < 5; ++k) dt[k] = 0.f;
#pragma unroll
    for (int j = 0; j < 4; ++j) {
      float4 v = xv[j];
      ss = fmaf(v.x, v.x, fmaf(v.y, v.y, fmaf(v.z, v.z, fmaf(v.w, v.w, ss))));
#pragma unroll
      for (int k = 0; k < 5; ++k) {
        float4 q = q4[k][j];
        dt[k] = fmaf(v.x, q.x, fmaf(v.y, q.y, fmaf(v.z, q.z, fmaf(v.w, q.w, dt[k]))));
      }
    }
    float rn = 100.0f / fmaxf(sqrtf(wave_sum64(ss)), 1e-12f);
#pragma unroll
    for (int k = 0; k < 5; ++k) {
      float lg = wave_sum64(dt[k]) * rn;  // wave-uniform (readlane broadcast)
      float mn = fmaxf(mo[k], lg);
      if (mn > mo[k]) {                   // wave-uniform branch, rare
        float sc = __expf(mo[k] - mn);    // first row: exp(-inf) = 0
        ds[k] *= sc;
        scale4(a[k][0], sc); scale4(a[k][1], sc);
        scale4(a[k][2], sc); scale4(a[k][3], sc);
        mo[k] = mn;
      }
      float w = __expf(lg - mo[k]);
      ds[k] += w;
      fma4(a[k][0], w, xv[0]); fma4(a[k][1], w, xv[1]);
      fma4(a[k][2], w, xv[2]); fma4(a[k][3], w, xv[3]);
    }
  };

  // ---- main loop: 2 rows/iteration, 8KB in flight, no barriers/LDS ----
#pragma unroll 1
  for (int r = pid; r < N; r += 2 * NPAIR) {
    const int r2 = r + NPAIR;
    const bool two = (r2 < N);            // wave-uniform
    float4 x0[4], x1[4];
    {
      const float* xp = X + (size_t)r * C + co;
#pragma unroll
      for (int j = 0; j < 4; ++j) x0[j] = *(const float4*)(xp + j * 256);
    }
    if (two) {
      const float* xp = X + (size_t)r2 * C + co;
#pragma unroll
      for (int j = 0; j < 4; ++j) x1[j] = *(const float4*)(xp + j * 256);
    }
    proc(x0);
    if (two) proc(x1);
  }

  // ---- block combine: waves {0,2} own q0-4, {1,3} own q5-9 ----
  __shared__ float wm[4][8];
  __shared__ float wd[4][8];
  __shared__ float part[NQ][C];           // 40 KB
  if (l == 0) {
#pragma unroll
    for (int k = 0; k < 5; ++k) { wm[wv][k] = mo[k]; wd[wv][k] = ds[k]; }
  }
  __syncthreads();
  float sc[5];
#pragma unroll
  for (int k = 0; k < 5; ++k) {
    float M = fmaxf(wm[wv][k], wm[wv ^ 2][k]);
    sc[k] = __expf(mo[k] - M);
  }
  if (wv < 2) {
#pragma unroll
    for (int k = 0; k < 5; ++k)
#pragma unroll
      for (int j = 0; j < 4; ++j) {
        float4 o = a[k][j]; scale4(o, sc[k]);
        *(float4*)&part[qbase + k][j * 256 + co] = o;
      }
  }
  __syncthreads();
  if (wv >= 2) {
#pragma unroll
    for (int k = 0; k < 5; ++k)
#pragma unroll
      for (int j = 0; j < 4; ++j) {
        float4 p = *(const float4*)&part[qbase + k][j * 256 + co];
        float4 o = a[k][j];
        p.x = fmaf(o.x, sc[k], p.x); p.y = fmaf(o.y, sc[k], p.y);
        p.z = fmaf(o.z, sc[k], p.z); p.w = fmaf(o.w, sc[k], p.w);
        *(float4*)&part[qbase + k][j * 256 + co] = p;
      }
  }
  __syncthreads();

  // coalesced write-out of block partial [NQ][C]
  {
    const float4* src = (const float4*)&part[0][0];
    float4* dst = (float4*)&partial[(size_t)blockIdx.x * NQ * C];
    for (int idx = t; idx < NQ * (C / 4); idx += 256) dst[idx] = src[idx];
  }
  if (t < NQ) {
    int w0 = (t < 5) ? 0 : 1, k5 = (t < 5) ? t : t - 5;
    float m0 = wm[w0][k5], m1 = wm[w0 + 2][k5];
    float M = fmaxf(m0, m1);
    dsum[blockIdx.x * NQ + t] =
        wd[w0][k5] * __expf(m0 - M) + wd[w0 + 2][k5] * __expf(m1 - M);
    mblk[blockIdx.x * 16 + t] = M;
  }
}

// ---------------- K5a: combine partials with per-block max correction ------
// pooled[c] = sum_k [ sum_g exp(m_g-M_k) a_g[k][c] ] / (NQ * D_k),
//   D_k = sum_g exp(m_g-M_k) ds_g[k],  M_k = max_g m_g[k]
__global__ __launch_bounds__(256) void k5a_pooled(const float* __restrict__ partial,
                                                  const float* __restrict__ dsum,
                                                  const float* __restrict__ mblk,
                                                  float* __restrict__ pooled) {
  __shared__ float sM[16], sF[16];
  __shared__ float red[256];
  __shared__ float r4[256][4];
  int t = threadIdx.x;
  int k = t & 15, grp = t >> 4;

  float mm = -FLT_MAX;
  if (k < NQ)
    for (int g = grp; g < G4; g += 16) mm = fmaxf(mm, mblk[g * 16 + k]);
  red[t] = mm; __syncthreads();
  if (t < 16) {
    float m2 = red[t];
    for (int j = 1; j < 16; ++j) m2 = fmaxf(m2, red[t + 16 * j]);
    sM[t] = m2;
  }
  __syncthreads();

  float dd = 0.f;
  if (k < NQ) {
    float Mk = sM[k];
    for (int g = grp; g < G4; g += 16)
      dd += dsum[g * NQ + k] * __expf(mblk[g * 16 + k] - Mk);
  }
  red[t] = dd; __syncthreads();
  if (t < 16) {
    float d2 = 0.f;
    for (int j = 0; j < 16; ++j) d2 += red[t + 16 * j];
    sF[t] = 1.0f / ((float)NQ * d2);      // only t<NQ entries are consumed
  }
  __syncthreads();

  int c0 = blockIdx.x * 4;
  float a0 = 0.f, a1 = 0.f, a2 = 0.f, a3 = 0.f;
  for (int idx = t; idx < G4 * NQ; idx += 256) {
    int g = idx / NQ, kq = idx - g * NQ;
    float f = __expf(mblk[g * 16 + kq] - sM[kq]) * sF[kq];
    const float4 p = *(const float4*)&partial[(((size_t)idx) << 10) + c0];
    a0 = fmaf(p.x, f, a0); a1 = fmaf(p.y, f, a1);
    a2 = fmaf(p.z, f, a2); a3 = fmaf(p.w, f, a3);
  }
  r4[t][0] = a0; r4[t][1] = a1; r4[t][2] = a2; r4[t][3] = a3;
  __syncthreads();
  for (int st = 128; st > 0; st >>= 1) {
    if (t < st) {
      r4[t][0] += r4[t + st][0]; r4[t][1] += r4[t + st][1];
      r4[t][2] += r4[t + st][2]; r4[t][3] += r4[t + st][3];
    }
    __syncthreads();
  }
  if (t < 4) pooled[c0 + t] = r4[0][t];
}

// ---------------- K5b: out[j] = b[j] + sum_c pooled[c] * W[j][c] -----------
__global__ __launch_bounds__(256) void k5b_out(const float* __restrict__ W,
                                               const float* __restrict__ bias,
                                               const float* __restrict__ pooled,
                                               float* __restrict__ out) {
  __shared__ float sp[C];
  int t = threadIdx.x;
  for (int i = t; i < C; i += 256) sp[i] = pooled[i];
  __syncthreads();
  int wv = t >> 6, lane = t & 63;
#pragma unroll
  for (int jj = 0; jj < 8; ++jj) {
    int j = blockIdx.x * 32 + wv * 8 + jj;
    float s = 0.f;
#pragma unroll
    for (int seg = 0; seg < 4; ++seg) {
      int cbase = seg * 256 + lane * 4;
      float4 w4 = *(const float4*)&W[(size_t)j * C + cbase];
      float4 p4 = *(const float4*)&sp[cbase];
      s += w4.x * p4.x + w4.y * p4.y + w4.z * p4.z + w4.w * p4.w;
    }
#pragma unroll
    for (int off = 32; off > 0; off >>= 1) s += __shfl_down(s, off);
    if (lane == 0) out[j] = s + bias[j];
  }
}

// ---------------------------------------------------------------------------
extern "C" void kernel_launch(void* const* d_in, const int* in_sizes, int n_in,
                              void* d_out, int out_size, void* d_ws, size_t ws_size,
                              hipStream_t stream) {
  const float* X = (const float*)d_in[0];
  const float* Q = (const float*)d_in[1];
  const float* W = (const float*)d_in[2];
  const float* b = (const float*)d_in[3];
  float* out = (float*)d_out;

  int N = in_sizes[0] / C;                 // 100000

  float* ws      = (float*)d_ws;
  float* mblk    = ws;                               // G4*16
  float* dsum    = mblk + G4 * 16;                   // G4*NQ
  float* pooled  = dsum + G4 * NQ;                   // C
  float* partial = pooled + C;                       // G4*NQ*C (~21 MB)

  hipLaunchKernelGGL(kf_fused,  dim3(G4),     dim3(256), 0, stream,
                     X, Q, partial, dsum, mblk, N);
  hipLaunchKernelGGL(k5a_pooled,dim3(C / 4),  dim3(256), 0, stream,
                     partial, dsum, mblk, pooled);
  hipLaunchKernelGGL(k5b_out,   dim3(C / 32), dim3(256), 0, stream, W, b, pooled, out);
}